// Round 13
// baseline (1410.821 us; speedup 1.0000x reference)
//
#include <hip/hip_runtime.h>
#include <hip/hip_bf16.h>

#define BB 32
#define NN 520
#define MM 520
#define EE 128
#define HH 8
#define DKK 16
#define FFH_ 512
#define NL_ 6
#define DEPOT_ 20
#define LL 40

typedef short short8 __attribute__((ext_vector_type(8)));
typedef short bshort4 __attribute__((ext_vector_type(4)));
typedef float floatx4 __attribute__((ext_vector_type(4)));

// Manual RTNE float->bf16 (4 VALU ops) -- used where a value is converted once.
__device__ __forceinline__ unsigned short f2b(float x) {
    unsigned int u = __float_as_uint(x);
    return (unsigned short)((u + 0x7fffu + ((u >> 16) & 1u)) >> 16);
}
// Truncating float->bf16 (1 VALU op) -- ONLY for hi/lo SPLIT PAIRS (lo captures
// the hi residual exactly; r8/r9: saved ~8us/dispatch in fmha vs RTNE).
__device__ __forceinline__ unsigned short f2b_t(float x) {
    return (unsigned short)(__float_as_uint(x) >> 16);
}
__device__ __forceinline__ float b2f_(unsigned short h) {
    return __uint_as_float(((unsigned int)h) << 16);
}

// ---------------- embedding: depot/customer linear ----------------
__global__ __launch_bounds__(256) void embed_k(
    const float* __restrict__ dep, const float* __restrict__ cus,
    const float* __restrict__ Wd, const float* __restrict__ bd,
    const float* __restrict__ Wc3, const float* __restrict__ bc,
    float* __restrict__ x)
{
    int idx = blockIdx.x * 256 + threadIdx.x;   // < B*N*E = 2129920
    int e = idx & 127;
    int bn = idx >> 7;
    int n = bn % NN;
    int b = bn / NN;
    float a;
    if (n < DEPOT_) {
        a = bd[e];
        const float* f = dep + ((size_t)(b * DEPOT_ + n)) * 4;
        #pragma unroll
        for (int j = 0; j < 4; j++) a += f[j] * Wd[e * 4 + j];
    } else {
        a = bc[e];
        const float* f = cus + ((size_t)(b * 500 + (n - DEPOT_))) * 3;
        #pragma unroll
        for (int j = 0; j < 3; j++) a += f[j] * Wc3[e * 3 + j];
    }
    x[idx] = a;
}

// ---------------- weight pre-conversion: fp32 -> hi/lo bf16 planes ----------------
#define WLS 196608
#define WDEC 1179648
#define WTOT 1277952
__global__ __launch_bounds__(256) void wconv_k(
    const float* __restrict__ Wq, const float* __restrict__ Wk, const float* __restrict__ Wv,
    const float* __restrict__ Wc, const float* __restrict__ fW1, const float* __restrict__ fW2,
    const float* __restrict__ dWk, const float* __restrict__ dWv, const float* __restrict__ dWc,
    const float* __restrict__ Wql, const float* __restrict__ Wqr,
    unsigned short* __restrict__ WH, unsigned short* __restrict__ WL)
{
    int idx = blockIdx.x * 256 + threadIdx.x;
    if (idx >= WTOT) return;
    const float* src;
    if (idx < WDEC) {
        int i = idx / WLS, r = idx % WLS;
        if (r < 49152) {
            int row = r >> 7, col = r & 127;
            const float* w = row < 128 ? Wq : (row < 256 ? Wk : Wv);
            src = w + (size_t)i * 16384 + (size_t)(row & 127) * 128 + col;
        } else if (r < 65536) {
            src = Wc + (size_t)i * 16384 + (r - 49152);
        } else if (r < 131072) {
            src = fW1 + (size_t)i * 65536 + (r - 65536);
        } else {
            src = fW2 + (size_t)i * 65536 + (r - 131072);
        }
    } else {
        int r = idx - WDEC;
        if (r < 32768) {
            int row = r >> 7, col = r & 127;
            src = (row < 128 ? dWk : dWv) + (size_t)(row & 127) * 128 + col;
        } else if (r < 49152) {
            src = dWc + (r - 32768);
        } else {
            int rr = r - 49152;
            int row = rr >> 7, col = rr & 127;
            if (row < 128)      src = Wqr + (size_t)row * 257 + col;
            else if (row < 256) src = Wql + (size_t)(row - 128) * 256 + col;
            else                src = Wql + (size_t)(row - 256) * 256 + 128 + col;
        }
    }
    float v = *src;
    unsigned short h = f2b(v);
    WH[idx] = h;
    WL[idx] = f2b(v - b2f_(h));
}

// ---------------- bf16x3 MFMA GEMM, BM=64, double-buffered LDS ----------------
#define AP 40
__global__ __launch_bounds__(256) void gemm_pc_k(
    const float* __restrict__ A, int lda,
    const unsigned short* __restrict__ WH, const unsigned short* __restrict__ WL, int ldw,
    const float* __restrict__ bias,
    float* __restrict__ C, int ldc,
    int K, int relu)
{
    __shared__ __align__(16) unsigned short Ah[2][64][AP];
    __shared__ __align__(16) unsigned short Al[2][64][AP];
    __shared__ __align__(16) unsigned short Bh[2][64][AP];
    __shared__ __align__(16) unsigned short Bl[2][64][AP];

    int t = threadIdx.x;
    int w = t >> 6, lane = t & 63;
    int frow = lane & 15, fq = lane >> 4;
    int n0 = blockIdx.x * 64, m0 = blockIdx.y * 64;

    int arow = t & 63, acol = (t >> 6) * 8;

    const float* Abase = A + (size_t)(m0 + arow) * lda + acol;
    const unsigned short* WHb = WH + (size_t)(n0 + arow) * ldw + acol;
    const unsigned short* WLb = WL + (size_t)(n0 + arow) * ldw + acol;

    floatx4 acc[4];
    #pragma unroll
    for (int j = 0; j < 4; j++) acc[j] = (floatx4){0.0f, 0.0f, 0.0f, 0.0f};

    {
        float4 v0 = ((const float4*)Abase)[0];
        float4 v1 = ((const float4*)Abase)[1];
        float vr[8] = {v0.x, v0.y, v0.z, v0.w, v1.x, v1.y, v1.z, v1.w};
        short8 hv, lv;
        #pragma unroll
        for (int j = 0; j < 8; j++) {
            unsigned short h = f2b(vr[j]);
            hv[j] = (short)h;
            lv[j] = (short)f2b(vr[j] - b2f_(h));
        }
        *((short8*)&Ah[0][arow][acol]) = hv;
        *((short8*)&Al[0][arow][acol]) = lv;
        *((short8*)&Bh[0][arow][acol]) = *((const short8*)WHb);
        *((short8*)&Bl[0][arow][acol]) = *((const short8*)WLb);
    }
    __syncthreads();

    int nkt = K >> 5;
    for (int kt = 0; kt < nkt; kt++) {
        int cur = kt & 1;
        bool pf = (kt + 1 < nkt);

        float4 av0, av1;
        short8 nbh, nbl;
        if (pf) {
            const float* Ap = Abase + (kt + 1) * 32;
            av0 = ((const float4*)Ap)[0];
            av1 = ((const float4*)Ap)[1];
            nbh = *((const short8*)(WHb + (kt + 1) * 32));
            nbl = *((const short8*)(WLb + (kt + 1) * 32));
        }

        short8 ah = *((const short8*)&Ah[cur][w * 16 + frow][fq * 8]);
        short8 al = *((const short8*)&Al[cur][w * 16 + frow][fq * 8]);
        #pragma unroll
        for (int nt = 0; nt < 4; nt++) {
            short8 bh = *((const short8*)&Bh[cur][nt * 16 + frow][fq * 8]);
            short8 bl = *((const short8*)&Bl[cur][nt * 16 + frow][fq * 8]);
            acc[nt] = __builtin_amdgcn_mfma_f32_16x16x32_bf16(ah, bh, acc[nt], 0, 0, 0);
            acc[nt] = __builtin_amdgcn_mfma_f32_16x16x32_bf16(ah, bl, acc[nt], 0, 0, 0);
            acc[nt] = __builtin_amdgcn_mfma_f32_16x16x32_bf16(al, bh, acc[nt], 0, 0, 0);
        }

        if (pf) {
            int nb2 = cur ^ 1;
            float vr[8] = {av0.x, av0.y, av0.z, av0.w, av1.x, av1.y, av1.z, av1.w};
            short8 hv, lv;
            #pragma unroll
            for (int j = 0; j < 8; j++) {
                unsigned short h = f2b(vr[j]);
                hv[j] = (short)h;
                lv[j] = (short)f2b(vr[j] - b2f_(h));
            }
            *((short8*)&Ah[nb2][arow][acol]) = hv;
            *((short8*)&Al[nb2][arow][acol]) = lv;
            *((short8*)&Bh[nb2][arow][acol]) = nbh;
            *((short8*)&Bl[nb2][arow][acol]) = nbl;
        }
        __syncthreads();
    }

    #pragma unroll
    for (int nt = 0; nt < 4; nt++) {
        int col = n0 + nt * 16 + frow;
        float bv = bias ? bias[col] : 0.0f;
        int rbase = m0 + w * 16 + fq * 4;
        #pragma unroll
        for (int r = 0; r < 4; r++) {
            float v = acc[nt][r] + bv;
            if (relu) v = fmaxf(v, 0.0f);
            C[(size_t)(rbase + r) * ldc + col] = v;
        }
    }
}

// ---------------- fused 3-way GEMM (QKV / dec-KV / R+L1), BM=64, dbuf ----------------
__global__ __launch_bounds__(256) void gemm_qkv3_k(
    const float* __restrict__ A, int lda,
    const unsigned short* __restrict__ WH, const unsigned short* __restrict__ WL, int ldw,
    float* __restrict__ C0, float* __restrict__ C1, float* __restrict__ C2,
    int ldc, int K, int pack)
{
    __shared__ __align__(16) unsigned short Ah[2][64][AP];
    __shared__ __align__(16) unsigned short Al[2][64][AP];
    __shared__ __align__(16) unsigned short Bh[2][64][AP];
    __shared__ __align__(16) unsigned short Bl[2][64][AP];

    int t = threadIdx.x;
    int w = t >> 6, lane = t & 63;
    int frow = lane & 15, fq = lane >> 4;
    int nb = blockIdx.x;
    int which = nb >> 1;
    float* C = which == 0 ? C0 : (which == 1 ? C1 : C2);
    int n0w = nb * 64;
    int n0c = (nb & 1) * 64;
    int m0 = blockIdx.y * 64;

    int arow = t & 63, acol = (t >> 6) * 8;

    const float* Abase = A + (size_t)(m0 + arow) * lda + acol;
    const unsigned short* WHb = WH + (size_t)(n0w + arow) * ldw + acol;
    const unsigned short* WLb = WL + (size_t)(n0w + arow) * ldw + acol;

    floatx4 acc[4];
    #pragma unroll
    for (int j = 0; j < 4; j++) acc[j] = (floatx4){0.0f, 0.0f, 0.0f, 0.0f};

    {
        float4 v0 = ((const float4*)Abase)[0];
        float4 v1 = ((const float4*)Abase)[1];
        float vr[8] = {v0.x, v0.y, v0.z, v0.w, v1.x, v1.y, v1.z, v1.w};
        short8 hv, lv;
        #pragma unroll
        for (int j = 0; j < 8; j++) {
            unsigned short h = f2b(vr[j]);
            hv[j] = (short)h;
            lv[j] = (short)f2b(vr[j] - b2f_(h));
        }
        *((short8*)&Ah[0][arow][acol]) = hv;
        *((short8*)&Al[0][arow][acol]) = lv;
        *((short8*)&Bh[0][arow][acol]) = *((const short8*)WHb);
        *((short8*)&Bl[0][arow][acol]) = *((const short8*)WLb);
    }
    __syncthreads();

    int nkt = K >> 5;
    for (int kt = 0; kt < nkt; kt++) {
        int cur = kt & 1;
        bool pf = (kt + 1 < nkt);

        float4 av0, av1;
        short8 nbh, nbl;
        if (pf) {
            const float* Ap = Abase + (kt + 1) * 32;
            av0 = ((const float4*)Ap)[0];
            av1 = ((const float4*)Ap)[1];
            nbh = *((const short8*)(WHb + (kt + 1) * 32));
            nbl = *((const short8*)(WLb + (kt + 1) * 32));
        }

        short8 ah = *((const short8*)&Ah[cur][w * 16 + frow][fq * 8]);
        short8 al = *((const short8*)&Al[cur][w * 16 + frow][fq * 8]);
        #pragma unroll
        for (int nt = 0; nt < 4; nt++) {
            short8 bh = *((const short8*)&Bh[cur][nt * 16 + frow][fq * 8]);
            short8 bl = *((const short8*)&Bl[cur][nt * 16 + frow][fq * 8]);
            acc[nt] = __builtin_amdgcn_mfma_f32_16x16x32_bf16(ah, bh, acc[nt], 0, 0, 0);
            acc[nt] = __builtin_amdgcn_mfma_f32_16x16x32_bf16(ah, bl, acc[nt], 0, 0, 0);
            acc[nt] = __builtin_amdgcn_mfma_f32_16x16x32_bf16(al, bh, acc[nt], 0, 0, 0);
        }

        if (pf) {
            int nb2 = cur ^ 1;
            float vr[8] = {av0.x, av0.y, av0.z, av0.w, av1.x, av1.y, av1.z, av1.w};
            short8 hv, lv;
            #pragma unroll
            for (int j = 0; j < 8; j++) {
                unsigned short h = f2b(vr[j]);
                hv[j] = (short)h;
                lv[j] = (short)f2b(vr[j] - b2f_(h));
            }
            *((short8*)&Ah[nb2][arow][acol]) = hv;
            *((short8*)&Al[nb2][arow][acol]) = lv;
            *((short8*)&Bh[nb2][arow][acol]) = nbh;
            *((short8*)&Bl[nb2][arow][acol]) = nbl;
        }
        __syncthreads();
    }

    #pragma unroll
    for (int nt = 0; nt < 4; nt++) {
        int col = n0c + nt * 16 + frow;
        int hh = col >> 4, dd = col & 15;
        int rbase = m0 + w * 16 + fq * 4;
        #pragma unroll
        for (int r = 0; r < 4; r++) {
            int row = rbase + r;
            if (pack) {
                int b2 = row / NN, n2 = row - b2 * NN;
                C[((size_t)(b2 * HH + hh) * NN + n2) * 16 + dd] = acc[nt][r];
            } else {
                C[(size_t)row * ldc + col] = acc[nt][r];
            }
        }
    }
}

// ---------------- score GEMM (NT) MFMA bf16x3 with tanh epilogue (r11: kept) ----------------
__global__ __launch_bounds__(256) void sgemm_k(
    const float* __restrict__ A,    // score [B*520][128]
    const float* __restrict__ Enc,  // [B*520][128]
    float* __restrict__ C)          // [B][520][520]
{
    __shared__ __align__(16) unsigned short Ah[2][64][AP];
    __shared__ __align__(16) unsigned short Al[2][64][AP];
    __shared__ __align__(16) unsigned short Bh[2][64][AP];
    __shared__ __align__(16) unsigned short Bl[2][64][AP];

    int t = threadIdx.x;
    int w = t >> 6, lane = t & 63;
    int frow = lane & 15, fq = lane >> 4;
    int b = blockIdx.z;
    int n0 = blockIdx.x * 64, m0 = blockIdx.y * 64;

    int arow = t & 63, acol = (t >> 6) * 8;
    int mr = m0 + arow; if (mr >= NN) mr = NN - 1;
    int nr = n0 + arow; if (nr >= NN) nr = NN - 1;

    const float* Abase = A + ((size_t)(b * NN + mr)) * EE + acol;
    const float* Bbase = Enc + ((size_t)(b * NN + nr)) * EE + acol;

    floatx4 acc[4];
    #pragma unroll
    for (int j = 0; j < 4; j++) acc[j] = (floatx4){0.0f, 0.0f, 0.0f, 0.0f};

    {
        float4 a0 = ((const float4*)Abase)[0];
        float4 a1 = ((const float4*)Abase)[1];
        float4 b0 = ((const float4*)Bbase)[0];
        float4 b1 = ((const float4*)Bbase)[1];
        float ar[8] = {a0.x, a0.y, a0.z, a0.w, a1.x, a1.y, a1.z, a1.w};
        float br[8] = {b0.x, b0.y, b0.z, b0.w, b1.x, b1.y, b1.z, b1.w};
        short8 ahv, alv, bhv, blv;
        #pragma unroll
        for (int j = 0; j < 8; j++) {
            unsigned short h = f2b_t(ar[j]);
            ahv[j] = (short)h;
            alv[j] = (short)f2b_t(ar[j] - b2f_(h));
            unsigned short g2 = f2b_t(br[j]);
            bhv[j] = (short)g2;
            blv[j] = (short)f2b_t(br[j] - b2f_(g2));
        }
        *((short8*)&Ah[0][arow][acol]) = ahv;
        *((short8*)&Al[0][arow][acol]) = alv;
        *((short8*)&Bh[0][arow][acol]) = bhv;
        *((short8*)&Bl[0][arow][acol]) = blv;
    }
    __syncthreads();

    int nkt = EE >> 5;   // 4
    for (int kt = 0; kt < nkt; kt++) {
        int cur = kt & 1;
        bool pf = (kt + 1 < nkt);

        float4 a0, a1, b0, b1;
        if (pf) {
            const float* Ap = Abase + (kt + 1) * 32;
            const float* Bp = Bbase + (kt + 1) * 32;
            a0 = ((const float4*)Ap)[0]; a1 = ((const float4*)Ap)[1];
            b0 = ((const float4*)Bp)[0]; b1 = ((const float4*)Bp)[1];
        }

        short8 ah = *((const short8*)&Ah[cur][w * 16 + frow][fq * 8]);
        short8 al = *((const short8*)&Al[cur][w * 16 + frow][fq * 8]);
        #pragma unroll
        for (int nt = 0; nt < 4; nt++) {
            short8 bh = *((const short8*)&Bh[cur][nt * 16 + frow][fq * 8]);
            short8 bl = *((const short8*)&Bl[cur][nt * 16 + frow][fq * 8]);
            acc[nt] = __builtin_amdgcn_mfma_f32_16x16x32_bf16(ah, bh, acc[nt], 0, 0, 0);
            acc[nt] = __builtin_amdgcn_mfma_f32_16x16x32_bf16(ah, bl, acc[nt], 0, 0, 0);
            acc[nt] = __builtin_amdgcn_mfma_f32_16x16x32_bf16(al, bh, acc[nt], 0, 0, 0);
        }

        if (pf) {
            int nb2 = cur ^ 1;
            float ar[8] = {a0.x, a0.y, a0.z, a0.w, a1.x, a1.y, a1.z, a1.w};
            float br[8] = {b0.x, b0.y, b0.z, b0.w, b1.x, b1.y, b1.z, b1.w};
            short8 ahv, alv, bhv, blv;
            #pragma unroll
            for (int j = 0; j < 8; j++) {
                unsigned short h = f2b_t(ar[j]);
                ahv[j] = (short)h;
                alv[j] = (short)f2b_t(ar[j] - b2f_(h));
                unsigned short g2 = f2b_t(br[j]);
                bhv[j] = (short)g2;
                blv[j] = (short)f2b_t(br[j] - b2f_(g2));
            }
            *((short8*)&Ah[nb2][arow][acol]) = ahv;
            *((short8*)&Al[nb2][arow][acol]) = alv;
            *((short8*)&Bh[nb2][arow][acol]) = bhv;
            *((short8*)&Bl[nb2][arow][acol]) = blv;
        }
        __syncthreads();
    }

    #pragma unroll
    for (int nt = 0; nt < 4; nt++) {
        int n = n0 + nt * 16 + frow;
        if (n >= NN) continue;
        int rbase = m0 + w * 16 + fq * 4;
        #pragma unroll
        for (int r = 0; r < 4; r++) {
            int m = rbase + r;
            if (m >= NN) continue;
            float v = 10.0f * tanhf(acc[nt][r] * 0.088388347648318447f);
            C[((size_t)(b * NN + m)) * NN + n] = v;
        }
    }
}

// ---------------- row softmax: out = softmax(logits + mask) ----------------
__global__ __launch_bounds__(64) void smax_k(
    const float* __restrict__ L, const float* __restrict__ mask,
    float* __restrict__ out)
{
    int bm = blockIdx.x;
    int t = threadIdx.x;
    const float* Lr = L + (size_t)bm * NN;
    const float* Mr = mask + (size_t)bm * NN;
    float v[9];
    float mx = -1e30f;
    #pragma unroll
    for (int i = 0; i < 9; i++) {
        int idx = t + i * 64;
        if (idx < NN) { v[i] = Lr[idx] + Mr[idx]; mx = fmaxf(mx, v[i]); }
        else v[i] = -1e30f;
    }
    #pragma unroll
    for (int o = 32; o > 0; o >>= 1) mx = fmaxf(mx, __shfl_xor(mx, o));
    float s = 0.0f;
    #pragma unroll
    for (int i = 0; i < 9; i++) {
        int idx = t + i * 64;
        float e = (idx < NN) ? expf(v[i] - mx) : 0.0f;
        v[i] = e; s += e;
    }
    #pragma unroll
    for (int o = 32; o > 0; o >>= 1) s += __shfl_xor(s, o);
    float inv = 1.0f / s;
    #pragma unroll
    for (int i = 0; i < 9; i++) {
        int idx = t + i * 64;
        if (idx < NN) out[(size_t)bm * NN + idx] = v[i] * inv;
    }
}

// ---------------- persistent-KV MFMA flash attention v5 (bf16x3, fp32-equivalent) ----------------
// r13: grid (b=32, h=8, z=8), NFRG=2 (fi = f*32 + z*4 + w, covers fi 0..32).
// r12 post-mortem: fmha is fetch-latency-bound (FETCH 37.7MB at only 600 GB/s);
// VGPR 108 capped residency at 4 blocks/CU. Dropping one fragment of state
// (-16 VGPR) + mvv[2][4][4] (-16) -> decoder ~80 VGPR (6 waves/SIMD), encoder
// ~64 (8 waves/SIMD); 2048 blocks = 8/CU for double the memory-level parallelism.
// 1/sqrt(DK)=0.25 folded into Q at load (power-of-2: exact, split unaffected).
// id%8 = b%8 preserved (z is the slowest grid dim) -> per-batch L2 on one XCD.
#define ATK 64
#define NFRG 2
template<bool HASM>
__global__ __launch_bounds__(256) void fmha_t_k(
    const float* __restrict__ Qp, const float* __restrict__ Kp,
    const float* __restrict__ Vp, const float* __restrict__ mask,
    float* __restrict__ O, int Nq, int Nk)
{
    __shared__ __align__(16) unsigned short Khl[2][ATK][40];  // [kc][0:16 hi-dk | 16:32 lo-dk]
    __shared__ __align__(16) unsigned short Vhi[2][16][72];
    __shared__ __align__(16) unsigned short Vlo[2][16][72];

    int b = blockIdx.x, h = blockIdx.y, z = blockIdx.z;
    int bh = b * HH + h;
    int t = threadIdx.x;
    int w = t >> 6, lane = t & 63;
    int r16 = lane & 15, g = lane >> 4;

    short8 qf[NFRG], qs[NFRG];
    floatx4 o_acc[NFRG];
    float m_i[NFRG], l_i[NFRG];
    const float* mrowf[NFRG];
    const float* QpB = Qp + (size_t)bh * Nq * 16;
    #pragma unroll
    for (int f = 0; f < NFRG; f++) {
        int fi = f * 32 + z * 4 + w;
        int qg = fi * 16 + r16;
        int qc = qg < Nq ? qg : Nq - 1;
        const float* qp = QpB + (size_t)qc * 16 + 8 * (g & 1);
        float4 qv0 = *((const float4*)qp);
        float4 qv1 = *((const float4*)(qp + 4));
        float qa[8] = {qv0.x * 0.25f, qv0.y * 0.25f, qv0.z * 0.25f, qv0.w * 0.25f,
                       qv1.x * 0.25f, qv1.y * 0.25f, qv1.z * 0.25f, qv1.w * 0.25f};
        #pragma unroll
        for (int j = 0; j < 8; j++) {
            unsigned short hh = f2b_t(qa[j]);
            unsigned short ll = f2b_t(qa[j] - b2f_(hh));
            qf[f][j] = (short)(g < 2 ? hh : ll);
            qs[f][j] = (short)(g < 2 ? ll : hh);
        }
        o_acc[f] = (floatx4){0.0f, 0.0f, 0.0f, 0.0f};
        m_i[f] = -1e30f; l_i[f] = 0.0f;
        mrowf[f] = HASM ? (mask + ((size_t)(b * Nq + qc)) * Nk) : nullptr;
    }

    int srow = t >> 2, sc = (t & 3) * 4;
    const float* KpB = Kp + ((size_t)bh * Nk) * 16 + sc;
    const float* VpB = Vp + ((size_t)bh * Nk) * 16 + sc;

    {
        int krc = srow < Nk ? srow : Nk - 1;
        float4 kv = *((const float4*)(KpB + (size_t)krc * 16));
        float4 vv = *((const float4*)(VpB + (size_t)krc * 16));
        float ka[4] = {kv.x, kv.y, kv.z, kv.w};
        float va[4] = {vv.x, vv.y, vv.z, vv.w};
        bshort4 khv, klv;
        #pragma unroll
        for (int j = 0; j < 4; j++) {
            unsigned short hh = f2b_t(ka[j]);
            khv[j] = (short)hh;
            klv[j] = (short)f2b_t(ka[j] - b2f_(hh));
        }
        *((bshort4*)&Khl[0][srow][sc])      = khv;
        *((bshort4*)&Khl[0][srow][16 + sc]) = klv;
        #pragma unroll
        for (int j = 0; j < 4; j++) {
            unsigned short hh = f2b_t(va[j]);
            Vhi[0][sc + j][srow] = hh;
            Vlo[0][sc + j][srow] = f2b_t(va[j] - b2f_(hh));
        }
    }
    __syncthreads();

    int nkt = (Nk + ATK - 1) / ATK;
    for (int kt = 0; kt < nkt; kt++) {
        int cur = kt & 1;
        int k0 = kt * ATK;
        bool full = (k0 + ATK <= Nk);   // wave-uniform

        float4 nkv, nvv;
        bool pf = (kt + 1 < nkt);
        if (pf) {
            int kr = k0 + ATK + srow;
            int krc = kr < Nk ? kr : Nk - 1;
            nkv = *((const float4*)(KpB + (size_t)krc * 16));
            nvv = *((const float4*)(VpB + (size_t)krc * 16));
        }

        // ---- hoisted mask loads for this tile (issue under the QK MFMAs) ----
        float mvv[HASM ? NFRG : 1][4][4];
        if (HASM) {
            #pragma unroll
            for (int f = 0; f < NFRG; f++) {
                #pragma unroll
                for (int s = 0; s < 4; s++) {
                    int c0 = k0 + s * 16 + 4 * g;
                    if (full || c0 + 3 < Nk) {
                        float4 m4 = *((const float4*)(mrowf[f] + c0));
                        mvv[f][s][0] = m4.x; mvv[f][s][1] = m4.y;
                        mvv[f][s][2] = m4.z; mvv[f][s][3] = m4.w;
                    } else {
                        #pragma unroll
                        for (int r = 0; r < 4; r++)
                            mvv[f][s][r] = (c0 + r < Nk) ? mrowf[f][c0 + r] : 0.0f;
                    }
                }
            }
        }

        short8 kfr[4];
        bshort4 vhf[4], vlf[4];
        #pragma unroll
        for (int s = 0; s < 4; s++) {
            kfr[s] = *((const short8*)&Khl[cur][s * 16 + r16][8 * g]);
            vhf[s] = *((const bshort4*)&Vhi[cur][r16][s * 16 + 4 * g]);
            vlf[s] = *((const bshort4*)&Vlo[cur][r16][s * 16 + 4 * g]);
        }

        #pragma unroll
        for (int f = 0; f < NFRG; f++) {
            int fi = f * 32 + z * 4 + w;
            if (fi * 16 >= Nq) continue;   // wave-uniform

            float p[4][4];
            #pragma unroll
            for (int s = 0; s < 4; s++) {
                floatx4 a = (floatx4){0.0f, 0.0f, 0.0f, 0.0f};
                a = __builtin_amdgcn_mfma_f32_16x16x32_bf16(kfr[s], qf[f], a, 0, 0, 0);
                a = __builtin_amdgcn_mfma_f32_16x16x32_bf16(kfr[s], qs[f], a, 0, 0, 0);
                #pragma unroll
                for (int r = 0; r < 4; r++) p[s][r] = a[r];
            }

            // ---- mask (+ bounds only on the partial tile); 0.25 pre-folded into Q ----
            if (full) {
                if (HASM) {
                    #pragma unroll
                    for (int s = 0; s < 4; s++)
                        #pragma unroll
                        for (int r = 0; r < 4; r++) p[s][r] += mvv[f][s][r];
                }
            } else {
                #pragma unroll
                for (int s = 0; s < 4; s++) {
                    int c0 = k0 + s * 16 + 4 * g;
                    #pragma unroll
                    for (int r = 0; r < 4; r++) {
                        float mv = HASM ? mvv[f][s][r] : 0.0f;
                        p[s][r] = (c0 + r < Nk) ? (p[s][r] + mv) : -1e30f;
                    }
                }
            }

            float tmax = -1e30f;
            #pragma unroll
            for (int s = 0; s < 4; s++)
                #pragma unroll
                for (int r = 0; r < 4; r++) tmax = fmaxf(tmax, p[s][r]);
            tmax = fmaxf(tmax, __shfl_xor(tmax, 16));
            tmax = fmaxf(tmax, __shfl_xor(tmax, 32));
            float m_new = fmaxf(m_i[f], tmax);
            float alpha = __expf(m_i[f] - m_new);
            float lloc = 0.0f;
            #pragma unroll
            for (int s = 0; s < 4; s++) {
                #pragma unroll
                for (int r = 0; r < 4; r++) {
                    float e = __expf(p[s][r] - m_new);
                    p[s][r] = e; lloc += e;
                }
            }
            lloc += __shfl_xor(lloc, 16);
            lloc += __shfl_xor(lloc, 32);
            l_i[f] = l_i[f] * alpha + lloc;
            m_i[f] = m_new;
            #pragma unroll
            for (int r = 0; r < 4; r++) {
                float ar = __shfl(alpha, 4 * g + r);
                o_acc[f][r] *= ar;
            }

            #pragma unroll
            for (int s = 0; s < 4; s++) {
                bshort4 ph, pl;
                #pragma unroll
                for (int r = 0; r < 4; r++) {
                    unsigned short hh = f2b_t(p[s][r]);
                    ph[r] = (short)hh;
                    pl[r] = (short)f2b_t(p[s][r] - b2f_(hh));
                }
                o_acc[f] = __builtin_amdgcn_mfma_f32_16x16x16bf16_1k(ph, vhf[s], o_acc[f], 0, 0, 0);
                o_acc[f] = __builtin_amdgcn_mfma_f32_16x16x16bf16_1k(ph, vlf[s], o_acc[f], 0, 0, 0);
                o_acc[f] = __builtin_amdgcn_mfma_f32_16x16x16bf16_1k(pl, vhf[s], o_acc[f], 0, 0, 0);
            }
        }

        if (pf) {
            int nb2 = cur ^ 1;
            float ka[4] = {nkv.x, nkv.y, nkv.z, nkv.w};
            float va[4] = {nvv.x, nvv.y, nvv.z, nvv.w};
            bshort4 khv, klv;
            #pragma unroll
            for (int j = 0; j < 4; j++) {
                unsigned short hh = f2b_t(ka[j]);
                khv[j] = (short)hh;
                klv[j] = (short)f2b_t(ka[j] - b2f_(hh));
            }
            *((bshort4*)&Khl[nb2][srow][sc])      = khv;
            *((bshort4*)&Khl[nb2][srow][16 + sc]) = klv;
            #pragma unroll
            for (int j = 0; j < 4; j++) {
                unsigned short hh = f2b_t(va[j]);
                Vhi[nb2][sc + j][srow] = hh;
                Vlo[nb2][sc + j][srow] = f2b_t(va[j] - b2f_(hh));
            }
        }
        __syncthreads();
    }

    #pragma unroll
    for (int f = 0; f < NFRG; f++) {
        int fi = f * 32 + z * 4 + w;
        if (fi * 16 >= Nq) continue;
        #pragma unroll
        for (int r = 0; r < 4; r++) {
            float lr = __shfl(l_i[f], 4 * g + r);
            int qrow = fi * 16 + 4 * g + r;
            if (qrow < Nq)
                O[((size_t)(b * Nq + qrow)) * EE + h * 16 + r16] = o_acc[f][r] / lr;
        }
    }
}

// ---------------- InstanceNorm over node axis (coalesced; r8: -276us vs e-fixed) ----------------
__global__ __launch_bounds__(256) void inorm_k(
    const float* __restrict__ X, const float* __restrict__ Y,
    const float* __restrict__ g, const float* __restrict__ bb,
    float* __restrict__ Out)
{
    int b = blockIdx.x, eg = blockIdx.y;
    int t = threadIdx.x;
    int tx = t & 15, tn = t >> 4;
    int e = eg * 16 + tx;
    const float* Xb = X + ((size_t)b * NN) * EE + e;
    const float* Yb = Y + ((size_t)b * NN) * EE + e;
    float s = 0.0f, s2 = 0.0f;
    for (int n = tn; n < NN; n += 16) {
        float v = Xb[(size_t)n * EE] + Yb[(size_t)n * EE];
        s += v; s2 += v * v;
    }
    __shared__ float rs[16][17], rs2[16][17];
    rs[tn][tx] = s; rs2[tn][tx] = s2;
    __syncthreads();
    float st = 0.0f, st2 = 0.0f;
    #pragma unroll
    for (int j = 0; j < 16; j++) { st += rs[j][tx]; st2 += rs2[j][tx]; }
    float mu = st * (1.0f / NN);
    float var = st2 * (1.0f / NN) - mu * mu;
    float inv = rsqrtf(var + 1e-5f);
    float gg = g[e], bv = bb[e];
    float* Ob = Out + ((size_t)b * NN) * EE + e;
    for (int n = tn; n < NN; n += 16) {
        float v = Xb[(size_t)n * EE] + Yb[(size_t)n * EE];
        Ob[(size_t)n * EE] = (v - mu) * inv * gg + bv;
    }
}

__global__ void zero_k(float* p, int n) {
    int i = blockIdx.x * 256 + threadIdx.x;
    if (i < n) p[i] = 0.0f;
}

__global__ __launch_bounds__(128) void encsum_k(const float* __restrict__ enc, float* __restrict__ esum) {
    int b = blockIdx.x, ch = blockIdx.y, t = threadIdx.x;
    float a = 0.0f;
    for (int i = 0; i < 65; i++) {
        int n = ch * 65 + i;
        a += enc[((size_t)(b * NN + n)) * EE + t];
    }
    atomicAdd(&esum[b * EE + t], a);
}

// mt[b,e] = sum_f (esum[b,f]/N) * Wr[e, 128+f]
__global__ __launch_bounds__(128) void meanterm_k(
    const float* __restrict__ esum, const float* __restrict__ Wr, float* __restrict__ mt)
{
    int b = blockIdx.x, t = threadIdx.x;
    __shared__ float em[128];
    em[t] = esum[b * EE + t] * (1.0f / NN);
    __syncthreads();
    const float* w = Wr + (size_t)t * 257 + 128;
    float a = 0.0f;
    for (int f = 0; f < 128; f++) a += em[f] * w[f];
    mt[b * EE + t] = a;
}

__global__ __launch_bounds__(128) void subtour_k(
    const float* __restrict__ enc, const int* __restrict__ subn,
    const int* __restrict__ subl, float* __restrict__ subm)
{
    int bm = blockIdx.x;
    int b = bm / MM;
    int t = threadIdx.x;
    int len = subl[bm];
    float acc = 0.0f; int cnt = 0;
    for (int l = 0; l < LL; l++) {
        int node = subn[(size_t)bm * LL + l];
        if (l < len && node >= DEPOT_) {
            acc += enc[((size_t)(b * NN + node)) * EE + t];
            cnt++;
        }
    }
    float cf = (float)(cnt < 1 ? 1 : cnt);
    subm[(size_t)bm * EE + t] = acc / cf;
}

// ---------------- decoder q: gather/blend, writes head-packed final_q ----------------
__global__ __launch_bounds__(128) void decq_gather_k(
    const float* __restrict__ R, const float* __restrict__ L1, const float* __restrict__ SM2,
    const float* __restrict__ mterm, const int* __restrict__ cur,
    const float* __restrict__ loadv, const int* __restrict__ sel,
    const float* __restrict__ Wqr, float* __restrict__ out)
{
    int bm = blockIdx.x;
    int b = bm / MM;
    int m = bm - b * MM;
    int t = threadIdx.x;
    int cn = cur[bm];
    int s2v = sel[(size_t)bm * 4 + 2];
    bool flag = (s2v >= DEPOT_) && (cn < DEPOT_);
    size_t eo = ((size_t)(b * NN + cn)) * EE + t;
    float q;
    if (flag) q = L1[eo] + SM2[(size_t)bm * EE + t];
    else      q = R[eo] + mterm[b * EE + t] + loadv[bm] * Wqr[(size_t)t * 257 + 256];
    out[((size_t)(b * HH + (t >> 4)) * MM + m) * 16 + (t & 15)] = q;
}

extern "C" void kernel_launch(void* const* d_in, const int* in_sizes, int n_in,
                              void* d_out, int out_size, void* d_ws, size_t ws_size,
                              hipStream_t stream)
{
    const float* depot = (const float*)d_in[0];
    const float* cust  = (const float*)d_in[1];
    const float* mask  = (const float*)d_in[2];
    const float* loadv = (const float*)d_in[3];
    const int*  cur   = (const int*)d_in[4];
    const int*  subn  = (const int*)d_in[5];
    const int*  subl  = (const int*)d_in[6];
    const int*  sel   = (const int*)d_in[7];
    const float* Wdep  = (const float*)d_in[8];
    const float* bdep  = (const float*)d_in[9];
    const float* Wcus  = (const float*)d_in[10];
    const float* bcus  = (const float*)d_in[11];
    const float* Wq    = (const float*)d_in[12];
    const float* Wk    = (const float*)d_in[13];
    const float* Wv    = (const float*)d_in[14];
    const float* Wc    = (const float*)d_in[15];
    const float* Wcb   = (const float*)d_in[16];
    const float* n1g   = (const float*)d_in[17];
    const float* n1b   = (const float*)d_in[18];
    const float* fW1   = (const float*)d_in[19];
    const float* fb1   = (const float*)d_in[20];
    const float* fW2   = (const float*)d_in[21];
    const float* fb2   = (const float*)d_in[22];
    const float* n2g   = (const float*)d_in[23];
    const float* n2b   = (const float*)d_in[24];
    const float* Wql   = (const float*)d_in[25];
    const float* Wqr   = (const float*)d_in[26];
    const float* dWk   = (const float*)d_in[27];
    const float* dWv   = (const float*)d_in[28];
    const float* dWc   = (const float*)d_in[29];
    const float* dWcb  = (const float*)d_in[30];

    const size_t SZ = (size_t)BB * NN * EE;           // 2,129,920
    float* f0 = (float*)d_ws;       // x / encoded
    float* f1 = f0 + SZ;            // q / k_d (packed) / logits (spans f1..f5)
    float* f2 = f1 + SZ;            // k / v_d (packed)
    float* f3 = f2 + SZ;            // v (packed) / encsum + meanterm
    float* f4 = f3 + SZ;            // mh,ff2 out / sub_mean, dec attn
    float* f5 = f4 + SZ;            // x1 / final_q (packed)
    float* big = f5 + SZ;           // ffh (B*N*FFH) / R,L1,SM2 / dec score
    unsigned short* WHp = (unsigned short*)(big + (size_t)BB * NN * FFH_);
    unsigned short* WLp = WHp + WTOT;

    dim3 g4(EE / 64, (BB * NN) / 64);      // (2, 260) = 520 blocks
    dim3 g16(FFH_ / 64, (BB * NN) / 64);   // (8, 260) = 2080 blocks
    dim3 gq3(6, (BB * NN) / 64);           // fused QKV, 1560 blocks
    dim3 gq2(4, (BB * NN) / 64);           // fused 2-way, 1040 blocks
    dim3 gmha(BB, HH, 8);                  // (32, 8, 8): id%8==b%8 -> per-batch L2; 2048 blocks = 8/CU
    dim3 gin(BB, 8);                       // coalesced inorm: (b, e-group)
    dim3 gsc((NN + 63) / 64, (NN + 63) / 64, BB);  // (9, 9, 32) MFMA logits

    wconv_k<<<(WTOT + 255) / 256, 256, 0, stream>>>(Wq, Wk, Wv, Wc, fW1, fW2,
                                                    dWk, dWv, dWc, Wql, Wqr, WHp, WLp);
    embed_k<<<(BB * NN * EE) / 256, 256, 0, stream>>>(depot, cust, Wdep, bdep, Wcus, bcus, f0);

    for (int i = 0; i < NL_; i++) {
        const unsigned short* lH = WHp + (size_t)i * WLS;
        const unsigned short* lL = WLp + (size_t)i * WLS;
        gemm_qkv3_k<<<gq3, 256, 0, stream>>>(f0, EE, lH, lL, EE, f1, f2, f3, EE, EE, 1);
        fmha_t_k<false><<<gmha, 256, 0, stream>>>(f1, f2, f3, nullptr, f4, NN, NN);
        gemm_pc_k<<<g4, 256, 0, stream>>>(f4, EE, lH + 49152, lL + 49152, EE, Wcb + i * EE, f1, EE, EE, 0);
        inorm_k<<<gin, 256, 0, stream>>>(f0, f1, n1g + i * EE, n1b + i * EE, f5);
        gemm_pc_k<<<g16, 256, 0, stream>>>(f5, EE, lH + 65536, lL + 65536, EE, fb1 + i * FFH_, big, FFH_, EE, 1);
        gemm_pc_k<<<g4, 256, 0, stream>>>(big, FFH_, lH + 131072, lL + 131072, FFH_, fb2 + i * EE, f1, EE, FFH_, 0);
        inorm_k<<<gin, 256, 0, stream>>>(f5, f1, n2g + i * EE, n2b + i * EE, f0);
    }

    // ---- decoder ----
    const unsigned short* dH = WHp + WDEC;
    const unsigned short* dL = WLp + WDEC;
    gemm_qkv3_k<<<gq2, 256, 0, stream>>>(f0, EE, dH, dL, EE, f1, f2, f2, EE, EE, 1);  // k_d, v_d packed

    zero_k<<<(BB * EE + 255) / 256, 256, 0, stream>>>(f3, BB * EE);
    encsum_k<<<dim3(BB, 8), 128, 0, stream>>>(f0, f3);
    meanterm_k<<<BB, 128, 0, stream>>>(f3, Wqr, f3 + BB * EE);
    subtour_k<<<BB * MM, 128, 0, stream>>>(f0, subn, subl, f4);

    // R (big), L1 (big+SZ) from encoded; SM2 (big+2SZ) from subm  (standard layout)
    gemm_qkv3_k<<<gq2, 256, 0, stream>>>(f0, EE, dH + 49152, dL + 49152, EE, big, big + SZ, big + SZ, EE, EE, 0);
    gemm_pc_k<<<g4, 256, 0, stream>>>(f4, EE, dH + 49152 + 32768, dL + 49152 + 32768, EE, nullptr, big + 2 * SZ, EE, EE, 0);
    decq_gather_k<<<BB * MM, 128, 0, stream>>>(big, big + SZ, big + 2 * SZ, f3 + BB * EE, cur, loadv, sel, Wqr, f5);

    fmha_t_k<true><<<gmha, 256, 0, stream>>>(f5, f1, f2, mask, f4, MM, NN);
    gemm_pc_k<<<g4, 256, 0, stream>>>(f4, EE, dH + 32768, dL + 32768, EE, dWcb, big, EE, EE, 0);

    // logits (B x 520 x 520) at f1 (spans f1..f5; all dead now)
    sgemm_k<<<gsc, 256, 0, stream>>>(big, f0, f1);
    smax_k<<<BB * MM, 64, 0, stream>>>(f1, mask, (float*)d_out);
}

// Round 14
// 1373.578 us; speedup vs baseline: 1.0271x; 1.0271x over previous
//
#include <hip/hip_runtime.h>
#include <hip/hip_bf16.h>

#define BB 32
#define NN 520
#define MM 520
#define EE 128
#define HH 8
#define DKK 16
#define FFH_ 512
#define NL_ 6
#define DEPOT_ 20
#define LL 40

typedef short short8 __attribute__((ext_vector_type(8)));
typedef short bshort4 __attribute__((ext_vector_type(4)));
typedef float floatx4 __attribute__((ext_vector_type(4)));

// Manual RTNE float->bf16 (4 VALU ops) -- used where a value is converted once.
__device__ __forceinline__ unsigned short f2b(float x) {
    unsigned int u = __float_as_uint(x);
    return (unsigned short)((u + 0x7fffu + ((u >> 16) & 1u)) >> 16);
}
// Truncating float->bf16 (1 VALU op) -- ONLY for hi/lo SPLIT PAIRS (lo captures
// the hi residual exactly; r8/r9: saved ~8us/dispatch in fmha vs RTNE).
__device__ __forceinline__ unsigned short f2b_t(float x) {
    return (unsigned short)(__float_as_uint(x) >> 16);
}
__device__ __forceinline__ float b2f_(unsigned short h) {
    return __uint_as_float(((unsigned int)h) << 16);
}

// ---------------- embedding: depot/customer linear ----------------
__global__ __launch_bounds__(256) void embed_k(
    const float* __restrict__ dep, const float* __restrict__ cus,
    const float* __restrict__ Wd, const float* __restrict__ bd,
    const float* __restrict__ Wc3, const float* __restrict__ bc,
    float* __restrict__ x)
{
    int idx = blockIdx.x * 256 + threadIdx.x;   // < B*N*E = 2129920
    int e = idx & 127;
    int bn = idx >> 7;
    int n = bn % NN;
    int b = bn / NN;
    float a;
    if (n < DEPOT_) {
        a = bd[e];
        const float* f = dep + ((size_t)(b * DEPOT_ + n)) * 4;
        #pragma unroll
        for (int j = 0; j < 4; j++) a += f[j] * Wd[e * 4 + j];
    } else {
        a = bc[e];
        const float* f = cus + ((size_t)(b * 500 + (n - DEPOT_))) * 3;
        #pragma unroll
        for (int j = 0; j < 3; j++) a += f[j] * Wc3[e * 3 + j];
    }
    x[idx] = a;
}

// ---------------- weight pre-conversion: fp32 -> hi/lo bf16 planes ----------------
#define WLS 196608
#define WDEC 1179648
#define WTOT 1277952
__global__ __launch_bounds__(256) void wconv_k(
    const float* __restrict__ Wq, const float* __restrict__ Wk, const float* __restrict__ Wv,
    const float* __restrict__ Wc, const float* __restrict__ fW1, const float* __restrict__ fW2,
    const float* __restrict__ dWk, const float* __restrict__ dWv, const float* __restrict__ dWc,
    const float* __restrict__ Wql, const float* __restrict__ Wqr,
    unsigned short* __restrict__ WH, unsigned short* __restrict__ WL)
{
    int idx = blockIdx.x * 256 + threadIdx.x;
    if (idx >= WTOT) return;
    const float* src;
    if (idx < WDEC) {
        int i = idx / WLS, r = idx % WLS;
        if (r < 49152) {
            int row = r >> 7, col = r & 127;
            const float* w = row < 128 ? Wq : (row < 256 ? Wk : Wv);
            src = w + (size_t)i * 16384 + (size_t)(row & 127) * 128 + col;
        } else if (r < 65536) {
            src = Wc + (size_t)i * 16384 + (r - 49152);
        } else if (r < 131072) {
            src = fW1 + (size_t)i * 65536 + (r - 65536);
        } else {
            src = fW2 + (size_t)i * 65536 + (r - 131072);
        }
    } else {
        int r = idx - WDEC;
        if (r < 32768) {
            int row = r >> 7, col = r & 127;
            src = (row < 128 ? dWk : dWv) + (size_t)(row & 127) * 128 + col;
        } else if (r < 49152) {
            src = dWc + (r - 32768);
        } else {
            int rr = r - 49152;
            int row = rr >> 7, col = rr & 127;
            if (row < 128)      src = Wqr + (size_t)row * 257 + col;
            else if (row < 256) src = Wql + (size_t)(row - 128) * 256 + col;
            else                src = Wql + (size_t)(row - 256) * 256 + 128 + col;
        }
    }
    float v = *src;
    unsigned short h = f2b(v);
    WH[idx] = h;
    WL[idx] = f2b(v - b2f_(h));
}

// ---------------- bf16x3 MFMA GEMM, BM=64, double-buffered LDS ----------------
#define AP 40
__global__ __launch_bounds__(256) void gemm_pc_k(
    const float* __restrict__ A, int lda,
    const unsigned short* __restrict__ WH, const unsigned short* __restrict__ WL, int ldw,
    const float* __restrict__ bias,
    float* __restrict__ C, int ldc,
    int K, int relu)
{
    __shared__ __align__(16) unsigned short Ah[2][64][AP];
    __shared__ __align__(16) unsigned short Al[2][64][AP];
    __shared__ __align__(16) unsigned short Bh[2][64][AP];
    __shared__ __align__(16) unsigned short Bl[2][64][AP];

    int t = threadIdx.x;
    int w = t >> 6, lane = t & 63;
    int frow = lane & 15, fq = lane >> 4;
    int n0 = blockIdx.x * 64, m0 = blockIdx.y * 64;

    int arow = t & 63, acol = (t >> 6) * 8;

    const float* Abase = A + (size_t)(m0 + arow) * lda + acol;
    const unsigned short* WHb = WH + (size_t)(n0 + arow) * ldw + acol;
    const unsigned short* WLb = WL + (size_t)(n0 + arow) * ldw + acol;

    floatx4 acc[4];
    #pragma unroll
    for (int j = 0; j < 4; j++) acc[j] = (floatx4){0.0f, 0.0f, 0.0f, 0.0f};

    {
        float4 v0 = ((const float4*)Abase)[0];
        float4 v1 = ((const float4*)Abase)[1];
        float vr[8] = {v0.x, v0.y, v0.z, v0.w, v1.x, v1.y, v1.z, v1.w};
        short8 hv, lv;
        #pragma unroll
        for (int j = 0; j < 8; j++) {
            unsigned short h = f2b(vr[j]);
            hv[j] = (short)h;
            lv[j] = (short)f2b(vr[j] - b2f_(h));
        }
        *((short8*)&Ah[0][arow][acol]) = hv;
        *((short8*)&Al[0][arow][acol]) = lv;
        *((short8*)&Bh[0][arow][acol]) = *((const short8*)WHb);
        *((short8*)&Bl[0][arow][acol]) = *((const short8*)WLb);
    }
    __syncthreads();

    int nkt = K >> 5;
    for (int kt = 0; kt < nkt; kt++) {
        int cur = kt & 1;
        bool pf = (kt + 1 < nkt);

        float4 av0, av1;
        short8 nbh, nbl;
        if (pf) {
            const float* Ap = Abase + (kt + 1) * 32;
            av0 = ((const float4*)Ap)[0];
            av1 = ((const float4*)Ap)[1];
            nbh = *((const short8*)(WHb + (kt + 1) * 32));
            nbl = *((const short8*)(WLb + (kt + 1) * 32));
        }

        short8 ah = *((const short8*)&Ah[cur][w * 16 + frow][fq * 8]);
        short8 al = *((const short8*)&Al[cur][w * 16 + frow][fq * 8]);
        #pragma unroll
        for (int nt = 0; nt < 4; nt++) {
            short8 bh = *((const short8*)&Bh[cur][nt * 16 + frow][fq * 8]);
            short8 bl = *((const short8*)&Bl[cur][nt * 16 + frow][fq * 8]);
            acc[nt] = __builtin_amdgcn_mfma_f32_16x16x32_bf16(ah, bh, acc[nt], 0, 0, 0);
            acc[nt] = __builtin_amdgcn_mfma_f32_16x16x32_bf16(ah, bl, acc[nt], 0, 0, 0);
            acc[nt] = __builtin_amdgcn_mfma_f32_16x16x32_bf16(al, bh, acc[nt], 0, 0, 0);
        }

        if (pf) {
            int nb2 = cur ^ 1;
            float vr[8] = {av0.x, av0.y, av0.z, av0.w, av1.x, av1.y, av1.z, av1.w};
            short8 hv, lv;
            #pragma unroll
            for (int j = 0; j < 8; j++) {
                unsigned short h = f2b(vr[j]);
                hv[j] = (short)h;
                lv[j] = (short)f2b(vr[j] - b2f_(h));
            }
            *((short8*)&Ah[nb2][arow][acol]) = hv;
            *((short8*)&Al[nb2][arow][acol]) = lv;
            *((short8*)&Bh[nb2][arow][acol]) = nbh;
            *((short8*)&Bl[nb2][arow][acol]) = nbl;
        }
        __syncthreads();
    }

    #pragma unroll
    for (int nt = 0; nt < 4; nt++) {
        int col = n0 + nt * 16 + frow;
        float bv = bias ? bias[col] : 0.0f;
        int rbase = m0 + w * 16 + fq * 4;
        #pragma unroll
        for (int r = 0; r < 4; r++) {
            float v = acc[nt][r] + bv;
            if (relu) v = fmaxf(v, 0.0f);
            C[(size_t)(rbase + r) * ldc + col] = v;
        }
    }
}

// ---------------- fused 3-way GEMM (QKV / dec-KV / R+L1), BM=64, dbuf ----------------
__global__ __launch_bounds__(256) void gemm_qkv3_k(
    const float* __restrict__ A, int lda,
    const unsigned short* __restrict__ WH, const unsigned short* __restrict__ WL, int ldw,
    float* __restrict__ C0, float* __restrict__ C1, float* __restrict__ C2,
    int ldc, int K, int pack)
{
    __shared__ __align__(16) unsigned short Ah[2][64][AP];
    __shared__ __align__(16) unsigned short Al[2][64][AP];
    __shared__ __align__(16) unsigned short Bh[2][64][AP];
    __shared__ __align__(16) unsigned short Bl[2][64][AP];

    int t = threadIdx.x;
    int w = t >> 6, lane = t & 63;
    int frow = lane & 15, fq = lane >> 4;
    int nb = blockIdx.x;
    int which = nb >> 1;
    float* C = which == 0 ? C0 : (which == 1 ? C1 : C2);
    int n0w = nb * 64;
    int n0c = (nb & 1) * 64;
    int m0 = blockIdx.y * 64;

    int arow = t & 63, acol = (t >> 6) * 8;

    const float* Abase = A + (size_t)(m0 + arow) * lda + acol;
    const unsigned short* WHb = WH + (size_t)(n0w + arow) * ldw + acol;
    const unsigned short* WLb = WL + (size_t)(n0w + arow) * ldw + acol;

    floatx4 acc[4];
    #pragma unroll
    for (int j = 0; j < 4; j++) acc[j] = (floatx4){0.0f, 0.0f, 0.0f, 0.0f};

    {
        float4 v0 = ((const float4*)Abase)[0];
        float4 v1 = ((const float4*)Abase)[1];
        float vr[8] = {v0.x, v0.y, v0.z, v0.w, v1.x, v1.y, v1.z, v1.w};
        short8 hv, lv;
        #pragma unroll
        for (int j = 0; j < 8; j++) {
            unsigned short h = f2b(vr[j]);
            hv[j] = (short)h;
            lv[j] = (short)f2b(vr[j] - b2f_(h));
        }
        *((short8*)&Ah[0][arow][acol]) = hv;
        *((short8*)&Al[0][arow][acol]) = lv;
        *((short8*)&Bh[0][arow][acol]) = *((const short8*)WHb);
        *((short8*)&Bl[0][arow][acol]) = *((const short8*)WLb);
    }
    __syncthreads();

    int nkt = K >> 5;
    for (int kt = 0; kt < nkt; kt++) {
        int cur = kt & 1;
        bool pf = (kt + 1 < nkt);

        float4 av0, av1;
        short8 nbh, nbl;
        if (pf) {
            const float* Ap = Abase + (kt + 1) * 32;
            av0 = ((const float4*)Ap)[0];
            av1 = ((const float4*)Ap)[1];
            nbh = *((const short8*)(WHb + (kt + 1) * 32));
            nbl = *((const short8*)(WLb + (kt + 1) * 32));
        }

        short8 ah = *((const short8*)&Ah[cur][w * 16 + frow][fq * 8]);
        short8 al = *((const short8*)&Al[cur][w * 16 + frow][fq * 8]);
        #pragma unroll
        for (int nt = 0; nt < 4; nt++) {
            short8 bh = *((const short8*)&Bh[cur][nt * 16 + frow][fq * 8]);
            short8 bl = *((const short8*)&Bl[cur][nt * 16 + frow][fq * 8]);
            acc[nt] = __builtin_amdgcn_mfma_f32_16x16x32_bf16(ah, bh, acc[nt], 0, 0, 0);
            acc[nt] = __builtin_amdgcn_mfma_f32_16x16x32_bf16(ah, bl, acc[nt], 0, 0, 0);
            acc[nt] = __builtin_amdgcn_mfma_f32_16x16x32_bf16(al, bh, acc[nt], 0, 0, 0);
        }

        if (pf) {
            int nb2 = cur ^ 1;
            float vr[8] = {av0.x, av0.y, av0.z, av0.w, av1.x, av1.y, av1.z, av1.w};
            short8 hv, lv;
            #pragma unroll
            for (int j = 0; j < 8; j++) {
                unsigned short h = f2b(vr[j]);
                hv[j] = (short)h;
                lv[j] = (short)f2b(vr[j] - b2f_(h));
            }
            *((short8*)&Ah[nb2][arow][acol]) = hv;
            *((short8*)&Al[nb2][arow][acol]) = lv;
            *((short8*)&Bh[nb2][arow][acol]) = nbh;
            *((short8*)&Bl[nb2][arow][acol]) = nbl;
        }
        __syncthreads();
    }

    #pragma unroll
    for (int nt = 0; nt < 4; nt++) {
        int col = n0c + nt * 16 + frow;
        int hh = col >> 4, dd = col & 15;
        int rbase = m0 + w * 16 + fq * 4;
        #pragma unroll
        for (int r = 0; r < 4; r++) {
            int row = rbase + r;
            if (pack) {
                int b2 = row / NN, n2 = row - b2 * NN;
                C[((size_t)(b2 * HH + hh) * NN + n2) * 16 + dd] = acc[nt][r];
            } else {
                C[(size_t)row * ldc + col] = acc[nt][r];
            }
        }
    }
}

// ---------------- score GEMM (NT) MFMA bf16x3 with tanh epilogue (r11: kept) ----------------
__global__ __launch_bounds__(256) void sgemm_k(
    const float* __restrict__ A,    // score [B*520][128]
    const float* __restrict__ Enc,  // [B*520][128]
    float* __restrict__ C)          // [B][520][520]
{
    __shared__ __align__(16) unsigned short Ah[2][64][AP];
    __shared__ __align__(16) unsigned short Al[2][64][AP];
    __shared__ __align__(16) unsigned short Bh[2][64][AP];
    __shared__ __align__(16) unsigned short Bl[2][64][AP];

    int t = threadIdx.x;
    int w = t >> 6, lane = t & 63;
    int frow = lane & 15, fq = lane >> 4;
    int b = blockIdx.z;
    int n0 = blockIdx.x * 64, m0 = blockIdx.y * 64;

    int arow = t & 63, acol = (t >> 6) * 8;
    int mr = m0 + arow; if (mr >= NN) mr = NN - 1;
    int nr = n0 + arow; if (nr >= NN) nr = NN - 1;

    const float* Abase = A + ((size_t)(b * NN + mr)) * EE + acol;
    const float* Bbase = Enc + ((size_t)(b * NN + nr)) * EE + acol;

    floatx4 acc[4];
    #pragma unroll
    for (int j = 0; j < 4; j++) acc[j] = (floatx4){0.0f, 0.0f, 0.0f, 0.0f};

    {
        float4 a0 = ((const float4*)Abase)[0];
        float4 a1 = ((const float4*)Abase)[1];
        float4 b0 = ((const float4*)Bbase)[0];
        float4 b1 = ((const float4*)Bbase)[1];
        float ar[8] = {a0.x, a0.y, a0.z, a0.w, a1.x, a1.y, a1.z, a1.w};
        float br[8] = {b0.x, b0.y, b0.z, b0.w, b1.x, b1.y, b1.z, b1.w};
        short8 ahv, alv, bhv, blv;
        #pragma unroll
        for (int j = 0; j < 8; j++) {
            unsigned short h = f2b_t(ar[j]);
            ahv[j] = (short)h;
            alv[j] = (short)f2b_t(ar[j] - b2f_(h));
            unsigned short g2 = f2b_t(br[j]);
            bhv[j] = (short)g2;
            blv[j] = (short)f2b_t(br[j] - b2f_(g2));
        }
        *((short8*)&Ah[0][arow][acol]) = ahv;
        *((short8*)&Al[0][arow][acol]) = alv;
        *((short8*)&Bh[0][arow][acol]) = bhv;
        *((short8*)&Bl[0][arow][acol]) = blv;
    }
    __syncthreads();

    int nkt = EE >> 5;   // 4
    for (int kt = 0; kt < nkt; kt++) {
        int cur = kt & 1;
        bool pf = (kt + 1 < nkt);

        float4 a0, a1, b0, b1;
        if (pf) {
            const float* Ap = Abase + (kt + 1) * 32;
            const float* Bp = Bbase + (kt + 1) * 32;
            a0 = ((const float4*)Ap)[0]; a1 = ((const float4*)Ap)[1];
            b0 = ((const float4*)Bp)[0]; b1 = ((const float4*)Bp)[1];
        }

        short8 ah = *((const short8*)&Ah[cur][w * 16 + frow][fq * 8]);
        short8 al = *((const short8*)&Al[cur][w * 16 + frow][fq * 8]);
        #pragma unroll
        for (int nt = 0; nt < 4; nt++) {
            short8 bh = *((const short8*)&Bh[cur][nt * 16 + frow][fq * 8]);
            short8 bl = *((const short8*)&Bl[cur][nt * 16 + frow][fq * 8]);
            acc[nt] = __builtin_amdgcn_mfma_f32_16x16x32_bf16(ah, bh, acc[nt], 0, 0, 0);
            acc[nt] = __builtin_amdgcn_mfma_f32_16x16x32_bf16(ah, bl, acc[nt], 0, 0, 0);
            acc[nt] = __builtin_amdgcn_mfma_f32_16x16x32_bf16(al, bh, acc[nt], 0, 0, 0);
        }

        if (pf) {
            int nb2 = cur ^ 1;
            float ar[8] = {a0.x, a0.y, a0.z, a0.w, a1.x, a1.y, a1.z, a1.w};
            float br[8] = {b0.x, b0.y, b0.z, b0.w, b1.x, b1.y, b1.z, b1.w};
            short8 ahv, alv, bhv, blv;
            #pragma unroll
            for (int j = 0; j < 8; j++) {
                unsigned short h = f2b_t(ar[j]);
                ahv[j] = (short)h;
                alv[j] = (short)f2b_t(ar[j] - b2f_(h));
                unsigned short g2 = f2b_t(br[j]);
                bhv[j] = (short)g2;
                blv[j] = (short)f2b_t(br[j] - b2f_(g2));
            }
            *((short8*)&Ah[nb2][arow][acol]) = ahv;
            *((short8*)&Al[nb2][arow][acol]) = alv;
            *((short8*)&Bh[nb2][arow][acol]) = bhv;
            *((short8*)&Bl[nb2][arow][acol]) = blv;
        }
        __syncthreads();
    }

    #pragma unroll
    for (int nt = 0; nt < 4; nt++) {
        int n = n0 + nt * 16 + frow;
        if (n >= NN) continue;
        int rbase = m0 + w * 16 + fq * 4;
        #pragma unroll
        for (int r = 0; r < 4; r++) {
            int m = rbase + r;
            if (m >= NN) continue;
            float v = 10.0f * tanhf(acc[nt][r] * 0.088388347648318447f);
            C[((size_t)(b * NN + m)) * NN + n] = v;
        }
    }
}

// ---------------- row softmax: out = softmax(logits + mask) ----------------
__global__ __launch_bounds__(64) void smax_k(
    const float* __restrict__ L, const float* __restrict__ mask,
    float* __restrict__ out)
{
    int bm = blockIdx.x;
    int t = threadIdx.x;
    const float* Lr = L + (size_t)bm * NN;
    const float* Mr = mask + (size_t)bm * NN;
    float v[9];
    float mx = -1e30f;
    #pragma unroll
    for (int i = 0; i < 9; i++) {
        int idx = t + i * 64;
        if (idx < NN) { v[i] = Lr[idx] + Mr[idx]; mx = fmaxf(mx, v[i]); }
        else v[i] = -1e30f;
    }
    #pragma unroll
    for (int o = 32; o > 0; o >>= 1) mx = fmaxf(mx, __shfl_xor(mx, o));
    float s = 0.0f;
    #pragma unroll
    for (int i = 0; i < 9; i++) {
        int idx = t + i * 64;
        float e = (idx < NN) ? expf(v[i] - mx) : 0.0f;
        v[i] = e; s += e;
    }
    #pragma unroll
    for (int o = 32; o > 0; o >>= 1) s += __shfl_xor(s, o);
    float inv = 1.0f / s;
    #pragma unroll
    for (int i = 0; i < 9; i++) {
        int idx = t + i * 64;
        if (idx < NN) out[(size_t)bm * NN + idx] = v[i] * inv;
    }
}

// ---------------- persistent-KV MFMA flash attention v4.1 (r12 structure restored) ----------------
// r13 post-mortem: z=8/NFRG=2 doubled per-output staging overhead (each block
// stages the FULL K/V stream; bank conflicts doubled, BW dropped) -> revert to
// NFRG=3, z=4. Kept from r13: 1/sqrt(DK)=0.25 folded into Q at load (exact).
// Template<HASM>: encoder drops the mask path at compile time. Full/partial
// K-tile split (8 of 9 tiles are full). Hoisted mvv loads overlap all 3 frags.
#define ATK 64
#define NFRG 3
template<bool HASM>
__global__ __launch_bounds__(256) void fmha_t_k(
    const float* __restrict__ Qp, const float* __restrict__ Kp,
    const float* __restrict__ Vp, const float* __restrict__ mask,
    float* __restrict__ O, int Nq, int Nk)
{
    __shared__ __align__(16) unsigned short Khl[2][ATK][40];  // [kc][0:16 hi-dk | 16:32 lo-dk]
    __shared__ __align__(16) unsigned short Vhi[2][16][72];
    __shared__ __align__(16) unsigned short Vlo[2][16][72];

    int b = blockIdx.x, h = blockIdx.y, z = blockIdx.z;
    int bh = b * HH + h;
    int t = threadIdx.x;
    int w = t >> 6, lane = t & 63;
    int r16 = lane & 15, g = lane >> 4;

    short8 qf[NFRG], qs[NFRG];
    floatx4 o_acc[NFRG];
    float m_i[NFRG], l_i[NFRG];
    const float* mrowf[NFRG];
    const float* QpB = Qp + (size_t)bh * Nq * 16;
    #pragma unroll
    for (int f = 0; f < NFRG; f++) {
        int fi = f * 16 + z * 4 + w;
        int qg = fi * 16 + r16;
        int qc = qg < Nq ? qg : Nq - 1;
        const float* qp = QpB + (size_t)qc * 16 + 8 * (g & 1);
        float4 qv0 = *((const float4*)qp);
        float4 qv1 = *((const float4*)(qp + 4));
        float qa[8] = {qv0.x * 0.25f, qv0.y * 0.25f, qv0.z * 0.25f, qv0.w * 0.25f,
                       qv1.x * 0.25f, qv1.y * 0.25f, qv1.z * 0.25f, qv1.w * 0.25f};
        #pragma unroll
        for (int j = 0; j < 8; j++) {
            unsigned short hh = f2b_t(qa[j]);
            unsigned short ll = f2b_t(qa[j] - b2f_(hh));
            qf[f][j] = (short)(g < 2 ? hh : ll);
            qs[f][j] = (short)(g < 2 ? ll : hh);
        }
        o_acc[f] = (floatx4){0.0f, 0.0f, 0.0f, 0.0f};
        m_i[f] = -1e30f; l_i[f] = 0.0f;
        mrowf[f] = HASM ? (mask + ((size_t)(b * Nq + qc)) * Nk) : nullptr;
    }

    int srow = t >> 2, sc = (t & 3) * 4;
    const float* KpB = Kp + ((size_t)bh * Nk) * 16 + sc;
    const float* VpB = Vp + ((size_t)bh * Nk) * 16 + sc;

    {
        int krc = srow < Nk ? srow : Nk - 1;
        float4 kv = *((const float4*)(KpB + (size_t)krc * 16));
        float4 vv = *((const float4*)(VpB + (size_t)krc * 16));
        float ka[4] = {kv.x, kv.y, kv.z, kv.w};
        float va[4] = {vv.x, vv.y, vv.z, vv.w};
        bshort4 khv, klv;
        #pragma unroll
        for (int j = 0; j < 4; j++) {
            unsigned short hh = f2b_t(ka[j]);
            khv[j] = (short)hh;
            klv[j] = (short)f2b_t(ka[j] - b2f_(hh));
        }
        *((bshort4*)&Khl[0][srow][sc])      = khv;
        *((bshort4*)&Khl[0][srow][16 + sc]) = klv;
        #pragma unroll
        for (int j = 0; j < 4; j++) {
            unsigned short hh = f2b_t(va[j]);
            Vhi[0][sc + j][srow] = hh;
            Vlo[0][sc + j][srow] = f2b_t(va[j] - b2f_(hh));
        }
    }
    __syncthreads();

    int nkt = (Nk + ATK - 1) / ATK;
    for (int kt = 0; kt < nkt; kt++) {
        int cur = kt & 1;
        int k0 = kt * ATK;
        bool full = (k0 + ATK <= Nk);   // wave-uniform

        float4 nkv, nvv;
        bool pf = (kt + 1 < nkt);
        if (pf) {
            int kr = k0 + ATK + srow;
            int krc = kr < Nk ? kr : Nk - 1;
            nkv = *((const float4*)(KpB + (size_t)krc * 16));
            nvv = *((const float4*)(VpB + (size_t)krc * 16));
        }

        // ---- hoisted mask loads for this tile (issue under the QK MFMAs) ----
        float mvv[HASM ? NFRG : 1][4][4];
        if (HASM) {
            #pragma unroll
            for (int f = 0; f < NFRG; f++) {
                #pragma unroll
                for (int s = 0; s < 4; s++) {
                    int c0 = k0 + s * 16 + 4 * g;
                    if (full || c0 + 3 < Nk) {
                        float4 m4 = *((const float4*)(mrowf[f] + c0));
                        mvv[f][s][0] = m4.x; mvv[f][s][1] = m4.y;
                        mvv[f][s][2] = m4.z; mvv[f][s][3] = m4.w;
                    } else {
                        #pragma unroll
                        for (int r = 0; r < 4; r++)
                            mvv[f][s][r] = (c0 + r < Nk) ? mrowf[f][c0 + r] : 0.0f;
                    }
                }
            }
        }

        short8 kfr[4];
        bshort4 vhf[4], vlf[4];
        #pragma unroll
        for (int s = 0; s < 4; s++) {
            kfr[s] = *((const short8*)&Khl[cur][s * 16 + r16][8 * g]);
            vhf[s] = *((const bshort4*)&Vhi[cur][r16][s * 16 + 4 * g]);
            vlf[s] = *((const bshort4*)&Vlo[cur][r16][s * 16 + 4 * g]);
        }

        #pragma unroll
        for (int f = 0; f < NFRG; f++) {
            int fi = f * 16 + z * 4 + w;
            if (fi * 16 >= Nq) continue;   // wave-uniform

            float p[4][4];
            #pragma unroll
            for (int s = 0; s < 4; s++) {
                floatx4 a = (floatx4){0.0f, 0.0f, 0.0f, 0.0f};
                a = __builtin_amdgcn_mfma_f32_16x16x32_bf16(kfr[s], qf[f], a, 0, 0, 0);
                a = __builtin_amdgcn_mfma_f32_16x16x32_bf16(kfr[s], qs[f], a, 0, 0, 0);
                #pragma unroll
                for (int r = 0; r < 4; r++) p[s][r] = a[r];
            }

            // ---- mask (+ bounds only on the partial tile); 0.25 pre-folded into Q ----
            if (full) {
                if (HASM) {
                    #pragma unroll
                    for (int s = 0; s < 4; s++)
                        #pragma unroll
                        for (int r = 0; r < 4; r++) p[s][r] += mvv[f][s][r];
                }
            } else {
                #pragma unroll
                for (int s = 0; s < 4; s++) {
                    int c0 = k0 + s * 16 + 4 * g;
                    #pragma unroll
                    for (int r = 0; r < 4; r++) {
                        float mv = HASM ? mvv[f][s][r] : 0.0f;
                        p[s][r] = (c0 + r < Nk) ? (p[s][r] + mv) : -1e30f;
                    }
                }
            }

            float tmax = -1e30f;
            #pragma unroll
            for (int s = 0; s < 4; s++)
                #pragma unroll
                for (int r = 0; r < 4; r++) tmax = fmaxf(tmax, p[s][r]);
            tmax = fmaxf(tmax, __shfl_xor(tmax, 16));
            tmax = fmaxf(tmax, __shfl_xor(tmax, 32));
            float m_new = fmaxf(m_i[f], tmax);
            float alpha = __expf(m_i[f] - m_new);
            float lloc = 0.0f;
            #pragma unroll
            for (int s = 0; s < 4; s++) {
                #pragma unroll
                for (int r = 0; r < 4; r++) {
                    float e = __expf(p[s][r] - m_new);
                    p[s][r] = e; lloc += e;
                }
            }
            lloc += __shfl_xor(lloc, 16);
            lloc += __shfl_xor(lloc, 32);
            l_i[f] = l_i[f] * alpha + lloc;
            m_i[f] = m_new;
            #pragma unroll
            for (int r = 0; r < 4; r++) {
                float ar = __shfl(alpha, 4 * g + r);
                o_acc[f][r] *= ar;
            }

            #pragma unroll
            for (int s = 0; s < 4; s++) {
                bshort4 ph, pl;
                #pragma unroll
                for (int r = 0; r < 4; r++) {
                    unsigned short hh = f2b_t(p[s][r]);
                    ph[r] = (short)hh;
                    pl[r] = (short)f2b_t(p[s][r] - b2f_(hh));
                }
                o_acc[f] = __builtin_amdgcn_mfma_f32_16x16x16bf16_1k(ph, vhf[s], o_acc[f], 0, 0, 0);
                o_acc[f] = __builtin_amdgcn_mfma_f32_16x16x16bf16_1k(ph, vlf[s], o_acc[f], 0, 0, 0);
                o_acc[f] = __builtin_amdgcn_mfma_f32_16x16x16bf16_1k(pl, vhf[s], o_acc[f], 0, 0, 0);
            }
        }

        if (pf) {
            int nb2 = cur ^ 1;
            float ka[4] = {nkv.x, nkv.y, nkv.z, nkv.w};
            float va[4] = {nvv.x, nvv.y, nvv.z, nvv.w};
            bshort4 khv, klv;
            #pragma unroll
            for (int j = 0; j < 4; j++) {
                unsigned short hh = f2b_t(ka[j]);
                khv[j] = (short)hh;
                klv[j] = (short)f2b_t(ka[j] - b2f_(hh));
            }
            *((bshort4*)&Khl[nb2][srow][sc])      = khv;
            *((bshort4*)&Khl[nb2][srow][16 + sc]) = klv;
            #pragma unroll
            for (int j = 0; j < 4; j++) {
                unsigned short hh = f2b_t(va[j]);
                Vhi[nb2][sc + j][srow] = hh;
                Vlo[nb2][sc + j][srow] = f2b_t(va[j] - b2f_(hh));
            }
        }
        __syncthreads();
    }

    #pragma unroll
    for (int f = 0; f < NFRG; f++) {
        int fi = f * 16 + z * 4 + w;
        if (fi * 16 >= Nq) continue;
        #pragma unroll
        for (int r = 0; r < 4; r++) {
            float lr = __shfl(l_i[f], 4 * g + r);
            int qrow = fi * 16 + 4 * g + r;
            if (qrow < Nq)
                O[((size_t)(b * Nq + qrow)) * EE + h * 16 + r16] = o_acc[f][r] / lr;
        }
    }
}

// ---------------- InstanceNorm over node axis (coalesced; r8: -276us vs e-fixed) ----------------
__global__ __launch_bounds__(256) void inorm_k(
    const float* __restrict__ X, const float* __restrict__ Y,
    const float* __restrict__ g, const float* __restrict__ bb,
    float* __restrict__ Out)
{
    int b = blockIdx.x, eg = blockIdx.y;
    int t = threadIdx.x;
    int tx = t & 15, tn = t >> 4;
    int e = eg * 16 + tx;
    const float* Xb = X + ((size_t)b * NN) * EE + e;
    const float* Yb = Y + ((size_t)b * NN) * EE + e;
    float s = 0.0f, s2 = 0.0f;
    for (int n = tn; n < NN; n += 16) {
        float v = Xb[(size_t)n * EE] + Yb[(size_t)n * EE];
        s += v; s2 += v * v;
    }
    __shared__ float rs[16][17], rs2[16][17];
    rs[tn][tx] = s; rs2[tn][tx] = s2;
    __syncthreads();
    float st = 0.0f, st2 = 0.0f;
    #pragma unroll
    for (int j = 0; j < 16; j++) { st += rs[j][tx]; st2 += rs2[j][tx]; }
    float mu = st * (1.0f / NN);
    float var = st2 * (1.0f / NN) - mu * mu;
    float inv = rsqrtf(var + 1e-5f);
    float gg = g[e], bv = bb[e];
    float* Ob = Out + ((size_t)b * NN) * EE + e;
    for (int n = tn; n < NN; n += 16) {
        float v = Xb[(size_t)n * EE] + Yb[(size_t)n * EE];
        Ob[(size_t)n * EE] = (v - mu) * inv * gg + bv;
    }
}

__global__ void zero_k(float* p, int n) {
    int i = blockIdx.x * 256 + threadIdx.x;
    if (i < n) p[i] = 0.0f;
}

__global__ __launch_bounds__(128) void encsum_k(const float* __restrict__ enc, float* __restrict__ esum) {
    int b = blockIdx.x, ch = blockIdx.y, t = threadIdx.x;
    float a = 0.0f;
    for (int i = 0; i < 65; i++) {
        int n = ch * 65 + i;
        a += enc[((size_t)(b * NN + n)) * EE + t];
    }
    atomicAdd(&esum[b * EE + t], a);
}

// mt[b,e] = sum_f (esum[b,f]/N) * Wr[e, 128+f]
__global__ __launch_bounds__(128) void meanterm_k(
    const float* __restrict__ esum, const float* __restrict__ Wr, float* __restrict__ mt)
{
    int b = blockIdx.x, t = threadIdx.x;
    __shared__ float em[128];
    em[t] = esum[b * EE + t] * (1.0f / NN);
    __syncthreads();
    const float* w = Wr + (size_t)t * 257 + 128;
    float a = 0.0f;
    for (int f = 0; f < 128; f++) a += em[f] * w[f];
    mt[b * EE + t] = a;
}

__global__ __launch_bounds__(128) void subtour_k(
    const float* __restrict__ enc, const int* __restrict__ subn,
    const int* __restrict__ subl, float* __restrict__ subm)
{
    int bm = blockIdx.x;
    int b = bm / MM;
    int t = threadIdx.x;
    int len = subl[bm];
    float acc = 0.0f; int cnt = 0;
    for (int l = 0; l < LL; l++) {
        int node = subn[(size_t)bm * LL + l];
        if (l < len && node >= DEPOT_) {
            acc += enc[((size_t)(b * NN + node)) * EE + t];
            cnt++;
        }
    }
    float cf = (float)(cnt < 1 ? 1 : cnt);
    subm[(size_t)bm * EE + t] = acc / cf;
}

// ---------------- decoder q: gather/blend, writes head-packed final_q ----------------
__global__ __launch_bounds__(128) void decq_gather_k(
    const float* __restrict__ R, const float* __restrict__ L1, const float* __restrict__ SM2,
    const float* __restrict__ mterm, const int* __restrict__ cur,
    const float* __restrict__ loadv, const int* __restrict__ sel,
    const float* __restrict__ Wqr, float* __restrict__ out)
{
    int bm = blockIdx.x;
    int b = bm / MM;
    int m = bm - b * MM;
    int t = threadIdx.x;
    int cn = cur[bm];
    int s2v = sel[(size_t)bm * 4 + 2];
    bool flag = (s2v >= DEPOT_) && (cn < DEPOT_);
    size_t eo = ((size_t)(b * NN + cn)) * EE + t;
    float q;
    if (flag) q = L1[eo] + SM2[(size_t)bm * EE + t];
    else      q = R[eo] + mterm[b * EE + t] + loadv[bm] * Wqr[(size_t)t * 257 + 256];
    out[((size_t)(b * HH + (t >> 4)) * MM + m) * 16 + (t & 15)] = q;
}

extern "C" void kernel_launch(void* const* d_in, const int* in_sizes, int n_in,
                              void* d_out, int out_size, void* d_ws, size_t ws_size,
                              hipStream_t stream)
{
    const float* depot = (const float*)d_in[0];
    const float* cust  = (const float*)d_in[1];
    const float* mask  = (const float*)d_in[2];
    const float* loadv = (const float*)d_in[3];
    const int*  cur   = (const int*)d_in[4];
    const int*  subn  = (const int*)d_in[5];
    const int*  subl  = (const int*)d_in[6];
    const int*  sel   = (const int*)d_in[7];
    const float* Wdep  = (const float*)d_in[8];
    const float* bdep  = (const float*)d_in[9];
    const float* Wcus  = (const float*)d_in[10];
    const float* bcus  = (const float*)d_in[11];
    const float* Wq    = (const float*)d_in[12];
    const float* Wk    = (const float*)d_in[13];
    const float* Wv    = (const float*)d_in[14];
    const float* Wc    = (const float*)d_in[15];
    const float* Wcb   = (const float*)d_in[16];
    const float* n1g   = (const float*)d_in[17];
    const float* n1b   = (const float*)d_in[18];
    const float* fW1   = (const float*)d_in[19];
    const float* fb1   = (const float*)d_in[20];
    const float* fW2   = (const float*)d_in[21];
    const float* fb2   = (const float*)d_in[22];
    const float* n2g   = (const float*)d_in[23];
    const float* n2b   = (const float*)d_in[24];
    const float* Wql   = (const float*)d_in[25];
    const float* Wqr   = (const float*)d_in[26];
    const float* dWk   = (const float*)d_in[27];
    const float* dWv   = (const float*)d_in[28];
    const float* dWc   = (const float*)d_in[29];
    const float* dWcb  = (const float*)d_in[30];

    const size_t SZ = (size_t)BB * NN * EE;           // 2,129,920
    float* f0 = (float*)d_ws;       // x / encoded
    float* f1 = f0 + SZ;            // q / k_d (packed) / logits (spans f1..f5)
    float* f2 = f1 + SZ;            // k / v_d (packed)
    float* f3 = f2 + SZ;            // v (packed) / encsum + meanterm
    float* f4 = f3 + SZ;            // mh,ff2 out / sub_mean, dec attn
    float* f5 = f4 + SZ;            // x1 / final_q (packed)
    float* big = f5 + SZ;           // ffh (B*N*FFH) / R,L1,SM2 / dec score
    unsigned short* WHp = (unsigned short*)(big + (size_t)BB * NN * FFH_);
    unsigned short* WLp = WHp + WTOT;

    dim3 g4(EE / 64, (BB * NN) / 64);      // (2, 260) = 520 blocks
    dim3 g16(FFH_ / 64, (BB * NN) / 64);   // (8, 260) = 2080 blocks
    dim3 gq3(6, (BB * NN) / 64);           // fused QKV, 1560 blocks
    dim3 gq2(4, (BB * NN) / 64);           // fused 2-way, 1040 blocks
    dim3 gmha(BB, HH, 4);                  // (32, 8, 4): id%8==b%8 -> per-batch L2 on one XCD
    dim3 gin(BB, 8);                       // coalesced inorm: (b, e-group)
    dim3 gsc((NN + 63) / 64, (NN + 63) / 64, BB);  // (9, 9, 32) MFMA logits

    wconv_k<<<(WTOT + 255) / 256, 256, 0, stream>>>(Wq, Wk, Wv, Wc, fW1, fW2,
                                                    dWk, dWv, dWc, Wql, Wqr, WHp, WLp);
    embed_k<<<(BB * NN * EE) / 256, 256, 0, stream>>>(depot, cust, Wdep, bdep, Wcus, bcus, f0);

    for (int i = 0; i < NL_; i++) {
        const unsigned short* lH = WHp + (size_t)i * WLS;
        const unsigned short* lL = WLp + (size_t)i * WLS;
        gemm_qkv3_k<<<gq3, 256, 0, stream>>>(f0, EE, lH, lL, EE, f1, f2, f3, EE, EE, 1);
        fmha_t_k<false><<<gmha, 256, 0, stream>>>(f1, f2, f3, nullptr, f4, NN, NN);
        gemm_pc_k<<<g4, 256, 0, stream>>>(f4, EE, lH + 49152, lL + 49152, EE, Wcb + i * EE, f1, EE, EE, 0);
        inorm_k<<<gin, 256, 0, stream>>>(f0, f1, n1g + i * EE, n1b + i * EE, f5);
        gemm_pc_k<<<g16, 256, 0, stream>>>(f5, EE, lH + 65536, lL + 65536, EE, fb1 + i * FFH_, big, FFH_, EE, 1);
        gemm_pc_k<<<g4, 256, 0, stream>>>(big, FFH_, lH + 131072, lL + 131072, FFH_, fb2 + i * EE, f1, EE, FFH_, 0);
        inorm_k<<<gin, 256, 0, stream>>>(f5, f1, n2g + i * EE, n2b + i * EE, f0);
    }

    // ---- decoder ----
    const unsigned short* dH = WHp + WDEC;
    const unsigned short* dL = WLp + WDEC;
    gemm_qkv3_k<<<gq2, 256, 0, stream>>>(f0, EE, dH, dL, EE, f1, f2, f2, EE, EE, 1);  // k_d, v_d packed

    zero_k<<<(BB * EE + 255) / 256, 256, 0, stream>>>(f3, BB * EE);
    encsum_k<<<dim3(BB, 8), 128, 0, stream>>>(f0, f3);
    meanterm_k<<<BB, 128, 0, stream>>>(f3, Wqr, f3 + BB * EE);
    subtour_k<<<BB * MM, 128, 0, stream>>>(f0, subn, subl, f4);

    // R (big), L1 (big+SZ) from encoded; SM2 (big+2SZ) from subm  (standard layout)
    gemm_qkv3_k<<<gq2, 256, 0, stream>>>(f0, EE, dH + 49152, dL + 49152, EE, big, big + SZ, big + SZ, EE, EE, 0);
    gemm_pc_k<<<g4, 256, 0, stream>>>(f4, EE, dH + 49152 + 32768, dL + 49152 + 32768, EE, nullptr, big + 2 * SZ, EE, EE, 0);
    decq_gather_k<<<BB * MM, 128, 0, stream>>>(big, big + SZ, big + 2 * SZ, f3 + BB * EE, cur, loadv, sel, Wqr, f5);

    fmha_t_k<true><<<gmha, 256, 0, stream>>>(f5, f1, f2, mask, f4, MM, NN);
    gemm_pc_k<<<g4, 256, 0, stream>>>(f4, EE, dH + 32768, dL + 32768, EE, dWcb, big, EE, EE, 0);

    // logits (B x 520 x 520) at f1 (spans f1..f5; all dead now)
    sgemm_k<<<gsc, 256, 0, stream>>>(big, f0, f1);
    smax_k<<<BB * MM, 64, 0, stream>>>(f1, mask, (float*)d_out);
}